// Round 19
// baseline (689.048 us; speedup 1.0000x reference)
//
#include <hip/hip_runtime.h>
#include <math.h>

#define T_TOT   200704
#define C_DIM   192
#define HEADS   6
#define DH      32
#define NTOK    64
#define NWIN    3136
#define HID     384
#define IMG     224
#define NSIDE   28
#define WPI     784
#define QSCALE  0.17677669529663687f

typedef unsigned short ushortT;
typedef short bf16x8 __attribute__((ext_vector_type(8)));
typedef float f32x4 __attribute__((ext_vector_type(4)));

__device__ __forceinline__ unsigned short f2bf(float f){
    unsigned u = __float_as_uint(f);
    u += 0x7FFFu + ((u >> 16) & 1u);
    return (unsigned short)(u >> 16);
}
__device__ __forceinline__ unsigned pack2(float a, float b){
    return (unsigned)f2bf(a) | ((unsigned)f2bf(b) << 16);
}

// ---------------- weight prep: out[n*K+k] = bf16(in[k*N+n])
__global__ void k_wprep(const float* __restrict__ w, unsigned short* __restrict__ o, int K, int N)
{
    int idx = blockIdx.x * 256 + threadIdx.x;
    if (idx >= K * N) return;
    int n = idx / K, k = idx - n * K;
    o[idx] = f2bf(w[(size_t)k * N + n]);
}

// ---------------- bias+mask prep: bmT[type][head][m][q] f32
__global__ void k_bmprep(const float* __restrict__ table, float* __restrict__ bmT)
{
    int idx = blockIdx.x * 256 + threadIdx.x;   // 4*6*64*64 = 98304
    int q = idx & 63, m = (idx >> 6) & 63;
    int head = (idx >> 12) % HEADS, type = idx / (64 * 64 * HEADS);
    int rq = q >> 3, cq = q & 7, rm = m >> 3, cm = m & 7;
    float b = table[((rq - rm + 7) * 15 + (cq - cm + 7)) * HEADS + head];
    int th = type >> 1, tw = type & 1;
    int lq = (th ? (rq >= 4 ? 2 : 1) : 0) * 3 + (tw ? (cq >= 4 ? 2 : 1) : 0);
    int lm = (th ? (rm >= 4 ? 2 : 1) : 0) * 3 + (tw ? (cm >= 4 ? 2 : 1) : 0);
    bmT[idx] = b + ((lq != lm) ? -100.f : 0.f);
}

// ---------------- K1+K2 fused: LN1 (wave-per-token) + QKV GEMM, A in LDS.
__global__ void k_ln1qkv(const float* __restrict__ x, const float* __restrict__ g,
                         const float* __restrict__ bta,
                         const unsigned short* __restrict__ wt, const float* __restrict__ bias,
                         unsigned short* __restrict__ q, unsigned short* __restrict__ k,
                         unsigned short* __restrict__ v)
{
    __shared__ __align__(16) unsigned short As[64*200];
    const int tid = threadIdx.x, lane = tid & 63, wid = tid >> 6;
    const int lr = lane & 15, lg = lane >> 4;
    const int win = blockIdx.x;

    // ---- phase A: LN1, one wave per token, 16 tokens per wave.
    {
        int bimg = win / WPI, w2 = win % WPI;
        int wi8 = (w2 / NSIDE) * 8, wj8 = (w2 % NSIDE) * 8;
        #pragma unroll 4
        for (int it = 0; it < 16; it++){
            int n = wid * 16 + it;
            int r = n >> 3, c = n & 7;
            int hs = wi8 + r + 4; if (hs >= IMG) hs -= IMG;
            int ws = wj8 + c + 4; if (ws >= IMG) ws -= IMG;
            const float* xp = x + ((size_t)bimg * (IMG*IMG) + hs * IMG + ws) * C_DIM + lane * 3;
            float v0 = xp[0], v1 = xp[1], v2 = xp[2];
            float sum = v0 + v1 + v2;
            float sq  = v0*v0 + v1*v1 + v2*v2;
            #pragma unroll
            for (int m = 1; m < 64; m <<= 1){ sum += __shfl_xor(sum, m); sq += __shfl_xor(sq, m); }
            float mu = sum * (1.f/192.f);
            float var = sq * (1.f/192.f) - mu*mu;
            float rs = rsqrtf(var + 1e-5f);
            int j = lane * 3;
            unsigned short* op = &As[n*200 + j];
            op[0] = f2bf((v0-mu)*rs*g[j]   + bta[j]);
            op[1] = f2bf((v1-mu)*rs*g[j+1] + bta[j+1]);
            op[2] = f2bf((v2-mu)*rs*g[j+2] + bta[j+2]);
        }
    }
    __syncthreads();

    // ---- phase B: QKV GEMM, 3 chunks (q,k,v), W frags from L2
    #pragma unroll
    for (int chunk = 0; chunk < 3; chunk++){
        f32x4 acc[3][4];
        #pragma unroll
        for (int nf = 0; nf < 3; nf++)
            #pragma unroll
            for (int mf = 0; mf < 4; mf++)
                acc[nf][mf] = (f32x4){0.f,0.f,0.f,0.f};
        #pragma unroll
        for (int k0 = 0; k0 < C_DIM; k0 += 32){
            bf16x8 a[4], b[3];
            #pragma unroll
            for (int mf = 0; mf < 4; mf++)
                a[mf] = *(const bf16x8*)&As[(mf*16 + lr)*200 + k0 + lg*8];
            #pragma unroll
            for (int nf = 0; nf < 3; nf++)
                b[nf] = *(const bf16x8*)(wt + (size_t)(chunk*192 + wid*48 + nf*16 + lr)*C_DIM + k0 + lg*8);
            #pragma unroll
            for (int nf = 0; nf < 3; nf++)
                #pragma unroll
                for (int mf = 0; mf < 4; mf++)
                    acc[nf][mf] = __builtin_amdgcn_mfma_f32_16x16x32_bf16(a[mf], b[nf], acc[nf][mf], 0, 0, 0);
        }
        unsigned short* dst = (chunk == 0) ? q : (chunk == 1) ? k : v;
        float sc = (chunk == 0) ? QSCALE : 1.f;
        #pragma unroll
        for (int nf = 0; nf < 3; nf++){
            int cc = wid*48 + nf*16 + lr;
            float b = bias[chunk*192 + cc];
            int head = cc >> 5, d = cc & 31;
            unsigned short* dp = dst + ((size_t)(win*HEADS + head) * NTOK) * DH + d;
            #pragma unroll
            for (int mf = 0; mf < 4; mf++)
                #pragma unroll
                for (int r = 0; r < 4; r++){
                    int ntok = mf*16 + lg*4 + r;
                    dp[ntok*DH] = f2bf((acc[nf][mf][r] + b) * sc);
                }
        }
    }
}

// ---------------- K3: MFMA windowed attention. 4 waves/block, 1 (win,head)/wave.
__global__ void k_attn_mfma(const unsigned short* __restrict__ q, const unsigned short* __restrict__ k,
                            const unsigned short* __restrict__ v, const float* __restrict__ bmT,
                            unsigned short* __restrict__ attn_o)
{
    __shared__ __align__(16) unsigned short Vt[4][32*72];
    __shared__ __align__(16) unsigned short Ps[4][64*72];
    const int tid = threadIdx.x, lane = tid & 63, wid = tid >> 6;
    const int wh = blockIdx.x * 4 + wid;
    const int head = wh % HEADS, win = wh / HEADS;
    const int w2 = win % WPI;
    const int type = ((w2 / NSIDE) == 27 ? 2 : 0) + ((w2 % NSIDE) == 27 ? 1 : 0);
    const size_t base = (size_t)wh * (NTOK * DH);
    const int lr = lane & 15, lg = lane >> 4;

    {
        const uint4* vp = (const uint4*)(v + base + lane * DH);
        uint4 va = vp[0], vb = vp[1], vc = vp[2], vd = vp[3];
        unsigned short* dst = &Vt[wid][lane];
        unsigned w0[8] = {va.x, va.y, va.z, va.w, vb.x, vb.y, vb.z, vb.w};
        #pragma unroll
        for (int j = 0; j < 8; j++){
            dst[(2*j)*72]   = (unsigned short)(w0[j] & 0xFFFFu);
            dst[(2*j+1)*72] = (unsigned short)(w0[j] >> 16);
        }
        unsigned w1[8] = {vc.x, vc.y, vc.z, vc.w, vd.x, vd.y, vd.z, vd.w};
        #pragma unroll
        for (int j = 0; j < 8; j++){
            dst[(16+2*j)*72]   = (unsigned short)(w1[j] & 0xFFFFu);
            dst[(16+2*j+1)*72] = (unsigned short)(w1[j] >> 16);
        }
    }

    bf16x8 aq[4], bk[4];
    {
        const unsigned short* qg = q + base + lr * DH + (lg << 3);
        const unsigned short* kg = k + base + lr * DH + (lg << 3);
        #pragma unroll
        for (int i = 0; i < 4; i++){
            aq[i] = *(const bf16x8*)(qg + i * 16 * DH);
            bk[i] = *(const bf16x8*)(kg + i * 16 * DH);
        }
    }

    f32x4 acc[4][4];
    #pragma unroll
    for (int mi = 0; mi < 4; mi++)
        #pragma unroll
        for (int ni = 0; ni < 4; ni++)
            acc[mi][ni] = __builtin_amdgcn_mfma_f32_16x16x32_bf16(aq[mi], bk[ni],
                              (f32x4){0.f,0.f,0.f,0.f}, 0, 0, 0);

    const float* bmBase = bmT + ((size_t)(type * HEADS + head) * 64) * 64;
    #pragma unroll
    for (int mi = 0; mi < 4; mi++)
        #pragma unroll
        for (int ni = 0; ni < 4; ni++){
            float4 bm = *(const float4*)(bmBase + (lr + 16*ni)*64 + lg*4 + 16*mi);
            acc[mi][ni][0] += bm.x; acc[mi][ni][1] += bm.y;
            acc[mi][ni][2] += bm.z; acc[mi][ni][3] += bm.w;
        }

    #pragma unroll
    for (int mi = 0; mi < 4; mi++){
        #pragma unroll
        for (int r = 0; r < 4; r++){
            float mx = fmaxf(fmaxf(acc[mi][0][r], acc[mi][1][r]),
                             fmaxf(acc[mi][2][r], acc[mi][3][r]));
            mx = fmaxf(mx, __shfl_xor(mx, 1));
            mx = fmaxf(mx, __shfl_xor(mx, 2));
            mx = fmaxf(mx, __shfl_xor(mx, 4));
            mx = fmaxf(mx, __shfl_xor(mx, 8));
            float e0 = __expf(acc[mi][0][r] - mx);
            float e1 = __expf(acc[mi][1][r] - mx);
            float e2 = __expf(acc[mi][2][r] - mx);
            float e3 = __expf(acc[mi][3][r] - mx);
            float sum = e0 + e1 + e2 + e3;
            sum += __shfl_xor(sum, 1);
            sum += __shfl_xor(sum, 2);
            sum += __shfl_xor(sum, 4);
            sum += __shfl_xor(sum, 8);
            float inv = 1.f / sum;
            int row = lg*4 + r + 16*mi;
            unsigned short* pr = &Ps[wid][row*72 + lr];
            pr[0]  = f2bf(e0 * inv);
            pr[16] = f2bf(e1 * inv);
            pr[32] = f2bf(e2 * inv);
            pr[48] = f2bf(e3 * inv);
        }
    }

    f32x4 o[4][2];
    #pragma unroll
    for (int mi = 0; mi < 4; mi++)
        #pragma unroll
        for (int ni = 0; ni < 2; ni++)
            o[mi][ni] = (f32x4){0.f,0.f,0.f,0.f};
    #pragma unroll
    for (int kb = 0; kb < 2; kb++){
        bf16x8 ap[4], bv[2];
        #pragma unroll
        for (int mi = 0; mi < 4; mi++)
            ap[mi] = *(const bf16x8*)&Ps[wid][(lr + 16*mi)*72 + (lg<<3) + 32*kb];
        #pragma unroll
        for (int ni = 0; ni < 2; ni++)
            bv[ni] = *(const bf16x8*)&Vt[wid][(lr + 16*ni)*72 + (lg<<3) + 32*kb];
        #pragma unroll
        for (int mi = 0; mi < 4; mi++)
            #pragma unroll
            for (int ni = 0; ni < 2; ni++)
                o[mi][ni] = __builtin_amdgcn_mfma_f32_16x16x32_bf16(ap[mi], bv[ni], o[mi][ni], 0, 0, 0);
    }

    unsigned short* ob = attn_o + ((size_t)win * NTOK) * C_DIM + head * DH;
    #pragma unroll
    for (int mi = 0; mi < 4; mi++)
        #pragma unroll
        for (int ni = 0; ni < 2; ni++)
            #pragma unroll
            for (int r = 0; r < 4; r++){
                int row = lg*4 + r + 16*mi;
                ob[(size_t)row * C_DIM + lr + 16*ni] = f2bf(o[mi][ni][r]);
            }
}

// ---------------- K4: proj GEMM, A staged once, single pass (4 waves x 48 cols)
__global__ void k_proj2(const unsigned short* __restrict__ ain, const unsigned short* __restrict__ wt,
                        const float* __restrict__ bias, const float* __restrict__ x,
                        float* __restrict__ out)
{
    __shared__ __align__(16) unsigned short As[64*200];
    const int tid = threadIdx.x, lane = tid & 63, wid = tid >> 6;
    const int lr = lane & 15, lg = lane >> 4;
    const int t0 = blockIdx.x * 64, win = blockIdx.x;

    {
        int row = tid >> 2, part = tid & 3;
        const unsigned short* gp = ain + (size_t)(t0 + row) * C_DIM;
        #pragma unroll
        for (int j = 0; j < 6; j++){
            int c = part*8 + j*32;
            *(uint4*)&As[row*200 + c] = *(const uint4*)(gp + c);
        }
    }
    __syncthreads();

    f32x4 acc[3][4];
    #pragma unroll
    for (int nf = 0; nf < 3; nf++)
        #pragma unroll
        for (int mf = 0; mf < 4; mf++)
            acc[nf][mf] = (f32x4){0.f,0.f,0.f,0.f};
    #pragma unroll
    for (int k0 = 0; k0 < C_DIM; k0 += 32){
        bf16x8 a[4], b[3];
        #pragma unroll
        for (int mf = 0; mf < 4; mf++)
            a[mf] = *(const bf16x8*)&As[(mf*16 + lr)*200 + k0 + lg*8];
        #pragma unroll
        for (int nf = 0; nf < 3; nf++)
            b[nf] = *(const bf16x8*)(wt + (size_t)(wid*48 + nf*16 + lr)*C_DIM + k0 + lg*8);
        #pragma unroll
        for (int nf = 0; nf < 3; nf++)
            #pragma unroll
            for (int mf = 0; mf < 4; mf++)
                acc[nf][mf] = __builtin_amdgcn_mfma_f32_16x16x32_bf16(a[mf], b[nf], acc[nf][mf], 0, 0, 0);
    }

    const int bimg = win / WPI, w2 = win % WPI;
    const int wi = w2 / NSIDE, wj = w2 % NSIDE;
    #pragma unroll
    for (int mf = 0; mf < 4; mf++){
        #pragma unroll
        for (int r = 0; r < 4; r++){
            int n = mf*16 + lg*4 + r;
            int rr = n >> 3, cc_ = n & 7;
            int hf = wi*8 + rr + 4; if (hf >= IMG) hf -= IMG;
            int wf = wj*8 + cc_ + 4; if (wf >= IMG) wf -= IMG;
            size_t s = ((size_t)bimg*(IMG*IMG) + hf*IMG + wf) * C_DIM;
            #pragma unroll
            for (int nf = 0; nf < 3; nf++){
                int c = wid*48 + nf*16 + lr;
                out[s + c] = x[s + c] + acc[nf][mf][r] + bias[c];
            }
        }
    }
}

// ---------------- K5: fused LN2 + fc1 + GELU + fc2 + residual
// 32 tokens/block, 4 waves, 25.1KB aliased LDS. Two-pass LN (no vals[] retention)
// to cut VGPR peak -> higher occupancy.
#define XS_STR 200
#define H1_STR 392
#define O_STR  196
__global__ void k_mlp(float* __restrict__ out,
                      const float* __restrict__ g, const float* __restrict__ bta,
                      const unsigned short* __restrict__ w1, const float* __restrict__ b1,
                      const unsigned short* __restrict__ w2, const float* __restrict__ b2)
{
    __shared__ __align__(16) unsigned short H1u[32*H1_STR];   // 25088 B
    unsigned short* Xs = H1u;
    float* O = (float*)H1u;
    const int tid = threadIdx.x, lane = tid & 63, wid = tid >> 6;
    const int lr = lane & 15, lg = lane >> 4;
    const int t0 = blockIdx.x * 32;

    // ---- phase 1: two-pass LN2 -> Xs bf16. 8 threads/row, 24 f32 each, no retention.
    {
        int row = tid >> 3, part = tid & 7;
        const float* xp = out + (size_t)(t0 + row) * C_DIM + part * 24;
        float sum = 0.f, sq = 0.f;
        #pragma unroll
        for (int j = 0; j < 6; j++){
            float4 v4 = *(const float4*)(xp + j*4);
            sum += v4.x + v4.y + v4.z + v4.w;
            sq  += v4.x*v4.x + v4.y*v4.y + v4.z*v4.z + v4.w*v4.w;
        }
        sum += __shfl_xor(sum, 1); sq += __shfl_xor(sq, 1);
        sum += __shfl_xor(sum, 2); sq += __shfl_xor(sq, 2);
        sum += __shfl_xor(sum, 4); sq += __shfl_xor(sq, 4);
        float mu = sum * (1.f/192.f);
        float var = sq * (1.f/192.f) - mu*mu;
        float rs = rsqrtf(var + 1e-5f);
        int c0 = part * 24;
        // pass 2: re-read (L1/L2-hot), normalize, pack
        #pragma unroll
        for (int j = 0; j < 3; j++){
            int c = c0 + j*8;
            float4 va = *(const float4*)(xp + j*8);
            float4 vb = *(const float4*)(xp + j*8 + 4);
            float4 ga = *(const float4*)(g + c), gb = *(const float4*)(g + c + 4);
            float4 ba = *(const float4*)(bta + c), bb = *(const float4*)(bta + c + 4);
            unsigned short tmp[8];
            tmp[0] = f2bf((va.x-mu)*rs*ga.x + ba.x);
            tmp[1] = f2bf((va.y-mu)*rs*ga.y + ba.y);
            tmp[2] = f2bf((va.z-mu)*rs*ga.z + ba.z);
            tmp[3] = f2bf((va.w-mu)*rs*ga.w + ba.w);
            tmp[4] = f2bf((vb.x-mu)*rs*gb.x + bb.x);
            tmp[5] = f2bf((vb.y-mu)*rs*gb.y + bb.y);
            tmp[6] = f2bf((vb.z-mu)*rs*gb.z + bb.z);
            tmp[7] = f2bf((vb.w-mu)*rs*gb.w + bb.w);
            *(uint4*)&Xs[row*XS_STR + c] = *(uint4*)tmp;
        }
    }
    __syncthreads();

    // ---- phase 2: fc1 transposed k-loop (reads Xs)
    f32x4 acc1[6][2];
    {
        #pragma unroll
        for (int mf = 0; mf < 6; mf++)
            #pragma unroll
            for (int nf = 0; nf < 2; nf++)
                acc1[mf][nf] = (f32x4){0.f,0.f,0.f,0.f};
        #pragma unroll
        for (int k0 = 0; k0 < C_DIM; k0 += 32){
            bf16x8 a[6], b[2];
            #pragma unroll
            for (int mf = 0; mf < 6; mf++)
                a[mf] = *(const bf16x8*)(w1 + (size_t)(wid*96 + mf*16 + lr)*C_DIM + k0 + lg*8);
            #pragma unroll
            for (int nf = 0; nf < 2; nf++)
                b[nf] = *(const bf16x8*)&Xs[(nf*16 + lr)*XS_STR + k0 + lg*8];
            #pragma unroll
            for (int mf = 0; mf < 6; mf++)
                #pragma unroll
                for (int nf = 0; nf < 2; nf++)
                    acc1[mf][nf] = __builtin_amdgcn_mfma_f32_16x16x32_bf16(a[mf], b[nf], acc1[mf][nf], 0, 0, 0);
        }
    }
    __syncthreads();   // all Xs reads done; H1 may overwrite

    // ---- GELU + pack to H1 (bf16, stride 392)
    {
        #pragma unroll
        for (int mf = 0; mf < 6; mf++){
            int hc = wid*96 + mf*16 + lg*4;
            float4 bb = *(const float4*)(b1 + hc);
            float bias[4] = {bb.x, bb.y, bb.z, bb.w};
            #pragma unroll
            for (int nf = 0; nf < 2; nf++){
                int token = nf*16 + lr;
                float gl[4];
                #pragma unroll
                for (int r = 0; r < 4; r++){
                    float u = acc1[mf][nf][r] + bias[r];
                    gl[r] = 0.5f*u*(1.f + erff(u*0.70710678118654752f));
                }
                uint2 pk; pk.x = pack2(gl[0], gl[1]); pk.y = pack2(gl[2], gl[3]);
                *(uint2*)&H1u[token*H1_STR + hc] = pk;
            }
        }
    }
    __syncthreads();

    // ---- phase 3: fc2 (D[token][out])
    f32x4 acc2[2][3];
    {
        #pragma unroll
        for (int rf = 0; rf < 2; rf++)
            #pragma unroll
            for (int cf = 0; cf < 3; cf++)
                acc2[rf][cf] = (f32x4){0.f,0.f,0.f,0.f};
        #pragma unroll
        for (int k0 = 0; k0 < HID; k0 += 32){
            bf16x8 a[2], b[3];
            #pragma unroll
            for (int rf = 0; rf < 2; rf++)
                a[rf] = *(const bf16x8*)&H1u[(rf*16 + lr)*H1_STR + k0 + lg*8];
            #pragma unroll
            for (int cf = 0; cf < 3; cf++)
                b[cf] = *(const bf16x8*)(w2 + (size_t)(wid*48 + cf*16 + lr)*HID + k0 + lg*8);
            #pragma unroll
            for (int rf = 0; rf < 2; rf++)
                #pragma unroll
                for (int cf = 0; cf < 3; cf++)
                    acc2[rf][cf] = __builtin_amdgcn_mfma_f32_16x16x32_bf16(a[rf], b[cf], acc2[rf][cf], 0, 0, 0);
        }
    }
    __syncthreads();   // all H1 reads done; O may now overwrite it

    // ---- stage O (f32, stride 196) with bias
    #pragma unroll
    for (int cf = 0; cf < 3; cf++){
        int c = wid*48 + cf*16 + lr;
        float bias = b2[c];
        #pragma unroll
        for (int rf = 0; rf < 2; rf++)
            #pragma unroll
            for (int r = 0; r < 4; r++)
                O[(rf*16 + lg*4 + r)*O_STR + c] = acc2[rf][cf][r] + bias;
    }
    __syncthreads();

    // ---- cooperative coalesced RMW: 8 threads/row, float4, interleaved cols
    {
        int row = tid >> 3, part = tid & 7;
        float* op = out + (size_t)(t0 + row) * C_DIM;
        const float* Or = O + row * O_STR;
        #pragma unroll
        for (int j = 0; j < 6; j++){
            int c = part*4 + j*32;
            float4 add = *(const float4*)&Or[c];
            float4 old = *(const float4*)&op[c];
            old.x += add.x; old.y += add.y; old.z += add.z; old.w += add.w;
            *(float4*)&op[c] = old;
        }
    }
}

extern "C" void kernel_launch(void* const* d_in, const int* in_sizes, int n_in,
                              void* d_out, int out_size, void* d_ws, size_t ws_size,
                              hipStream_t stream)
{
    const float* x       = (const float*)d_in[0];
    const float* n1g     = (const float*)d_in[1];
    const float* n1b     = (const float*)d_in[2];
    const float* qkv_w   = (const float*)d_in[3];
    const float* qkv_b   = (const float*)d_in[4];
    const float* proj_w  = (const float*)d_in[5];
    const float* proj_b  = (const float*)d_in[6];
    const float* rtab    = (const float*)d_in[7];
    const float* n2g     = (const float*)d_in[8];
    const float* n2b     = (const float*)d_in[9];
    const float* fc1_w   = (const float*)d_in[10];
    const float* fc1_b   = (const float*)d_in[11];
    const float* fc2_w   = (const float*)d_in[12];
    const float* fc2_b   = (const float*)d_in[13];
    float* out = (float*)d_out;

    char* wsb = (char*)d_ws;
    const size_t SZ = (size_t)T_TOT * C_DIM * 2;   // 77,070,336 bytes
    unsigned short* attn_o = (unsigned short*)(wsb);
    unsigned short* qb   = (unsigned short*)(wsb + SZ);
    unsigned short* kb   = (unsigned short*)(wsb + 2*SZ);
    unsigned short* vb   = (unsigned short*)(wsb + 3*SZ);
    unsigned short* wt_qkv  = (unsigned short*)(wsb + 4*SZ);
    unsigned short* wt_proj = wt_qkv + 576*192;
    unsigned short* wt_fc1  = wt_proj + 192*192;
    unsigned short* wt_fc2  = wt_fc1 + 384*192;
    float*          bmT     = (float*)(wt_fc2 + 384*192);   // 4*6*64*64 f32

    k_wprep<<<(192*576 + 255)/256, 256, 0, stream>>>(qkv_w, wt_qkv, 192, 576);
    k_wprep<<<(192*192 + 255)/256, 256, 0, stream>>>(proj_w, wt_proj, 192, 192);
    k_wprep<<<(192*384 + 255)/256, 256, 0, stream>>>(fc1_w, wt_fc1, 192, 384);
    k_wprep<<<(384*192 + 255)/256, 256, 0, stream>>>(fc2_w, wt_fc2, 384, 192);
    k_bmprep<<<(4*HEADS*64*64)/256, 256, 0, stream>>>(rtab, bmT);

    k_ln1qkv<<<NWIN, 256, 0, stream>>>(x, n1g, n1b, wt_qkv, qkv_b, qb, kb, vb);
    k_attn_mfma<<<NWIN*HEADS/4, 256, 0, stream>>>(qb, kb, vb, bmT, attn_o);
    k_proj2<<<NWIN, 256, 0, stream>>>(attn_o, wt_proj, proj_b, x, out);
    k_mlp<<<T_TOT/32, 256, 0, stream>>>(out, n2g, n2b, wt_fc1, fc1_b, wt_fc2, fc2_b);
}

// Round 20
// 677.617 us; speedup vs baseline: 1.0169x; 1.0169x over previous
//
#include <hip/hip_runtime.h>
#include <math.h>

#define T_TOT   200704
#define C_DIM   192
#define HEADS   6
#define DH      32
#define NTOK    64
#define NWIN    3136
#define HID     384
#define IMG     224
#define NSIDE   28
#define WPI     784
#define QSCALE  0.17677669529663687f

typedef unsigned short ushortT;
typedef short bf16x8 __attribute__((ext_vector_type(8)));
typedef float f32x4 __attribute__((ext_vector_type(4)));

__device__ __forceinline__ unsigned short f2bf(float f){
    unsigned u = __float_as_uint(f);
    u += 0x7FFFu + ((u >> 16) & 1u);
    return (unsigned short)(u >> 16);
}
__device__ __forceinline__ unsigned pack2(float a, float b){
    return (unsigned)f2bf(a) | ((unsigned)f2bf(b) << 16);
}

// ---------------- merged prep: all 4 weight transposes + bias/mask table
__global__ void k_prep(const float* __restrict__ qkv_w, const float* __restrict__ proj_w,
                       const float* __restrict__ fc1_w, const float* __restrict__ fc2_w,
                       const float* __restrict__ table,
                       unsigned short* __restrict__ wt_qkv, unsigned short* __restrict__ wt_proj,
                       unsigned short* __restrict__ wt_fc1, unsigned short* __restrict__ wt_fc2,
                       float* __restrict__ bmT)
{
    int idx = blockIdx.x * 256 + threadIdx.x;
    if (idx < 110592){                       // qkv: [576][192] <- [192][576]
        int n = idx / 192, k = idx - n * 192;
        wt_qkv[idx] = f2bf(qkv_w[(size_t)k * 576 + n]);
    } else if (idx < 147456){                // proj: [192][192]
        int i = idx - 110592;
        int n = i / 192, k = i - n * 192;
        wt_proj[i] = f2bf(proj_w[(size_t)k * 192 + n]);
    } else if (idx < 221184){                // fc1: [384][192] <- [192][384]
        int i = idx - 147456;
        int n = i / 192, k = i - n * 192;
        wt_fc1[i] = f2bf(fc1_w[(size_t)k * 384 + n]);
    } else if (idx < 294912){                // fc2: [192][384] <- [384][192]
        int i = idx - 221184;
        int n = i / 384, k = i - n * 384;
        wt_fc2[i] = f2bf(fc2_w[(size_t)k * 192 + n]);
    } else if (idx < 393216){                // bmT: 4*6*64*64
        int i = idx - 294912;
        int q = i & 63, m = (i >> 6) & 63;
        int head = (i >> 12) % HEADS, type = i / (64 * 64 * HEADS);
        int rq = q >> 3, cq = q & 7, rm = m >> 3, cm = m & 7;
        float b = table[((rq - rm + 7) * 15 + (cq - cm + 7)) * HEADS + head];
        int th = type >> 1, tw = type & 1;
        int lq = (th ? (rq >= 4 ? 2 : 1) : 0) * 3 + (tw ? (cq >= 4 ? 2 : 1) : 0);
        int lm = (th ? (rm >= 4 ? 2 : 1) : 0) * 3 + (tw ? (cm >= 4 ? 2 : 1) : 0);
        bmT[i] = b + ((lq != lm) ? -100.f : 0.f);
    }
}

// ---------------- K1+K2 fused: LN1 (8 thr/row, two-pass) + QKV GEMM, A in LDS.
__global__ void k_ln1qkv(const float* __restrict__ x, const float* __restrict__ g,
                         const float* __restrict__ bta,
                         const unsigned short* __restrict__ wt, const float* __restrict__ bias,
                         unsigned short* __restrict__ q, unsigned short* __restrict__ k,
                         unsigned short* __restrict__ v)
{
    __shared__ __align__(16) unsigned short As[64*200];
    const int tid = threadIdx.x, lane = tid & 63, wid = tid >> 6;
    const int lr = lane & 15, lg = lane >> 4;
    const int win = blockIdx.x;

    // ---- phase A: LN1, 8 threads/row two-pass, 32 rows in flight, 2 batches.
    {
        int bimg = win / WPI, w2 = win % WPI;
        int wi8 = (w2 / NSIDE) * 8, wj8 = (w2 % NSIDE) * 8;
        #pragma unroll
        for (int b = 0; b < 2; b++){
            int n = b*32 + (tid >> 3), part = tid & 7;
            int r = n >> 3, c = n & 7;
            int hs = wi8 + r + 4; if (hs >= IMG) hs -= IMG;
            int ws = wj8 + c + 4; if (ws >= IMG) ws -= IMG;
            const float* xp = x + ((size_t)bimg * (IMG*IMG) + hs * IMG + ws) * C_DIM + part * 24;
            float sum = 0.f, sq = 0.f;
            #pragma unroll
            for (int j = 0; j < 6; j++){
                float4 v4 = *(const float4*)(xp + j*4);
                sum += v4.x + v4.y + v4.z + v4.w;
                sq  += v4.x*v4.x + v4.y*v4.y + v4.z*v4.z + v4.w*v4.w;
            }
            sum += __shfl_xor(sum, 1); sq += __shfl_xor(sq, 1);
            sum += __shfl_xor(sum, 2); sq += __shfl_xor(sq, 2);
            sum += __shfl_xor(sum, 4); sq += __shfl_xor(sq, 4);
            float mu = sum * (1.f/192.f);
            float var = sq * (1.f/192.f) - mu*mu;
            float rs = rsqrtf(var + 1e-5f);
            int c0 = part * 24;
            #pragma unroll
            for (int j = 0; j < 3; j++){
                int cc = c0 + j*8;
                float4 va = *(const float4*)(xp + j*8);
                float4 vb = *(const float4*)(xp + j*8 + 4);
                float4 ga = *(const float4*)(g + cc), gb = *(const float4*)(g + cc + 4);
                float4 ba = *(const float4*)(bta + cc), bb = *(const float4*)(bta + cc + 4);
                unsigned short tmp[8];
                tmp[0] = f2bf((va.x-mu)*rs*ga.x + ba.x);
                tmp[1] = f2bf((va.y-mu)*rs*ga.y + ba.y);
                tmp[2] = f2bf((va.z-mu)*rs*ga.z + ba.z);
                tmp[3] = f2bf((va.w-mu)*rs*ga.w + ba.w);
                tmp[4] = f2bf((vb.x-mu)*rs*gb.x + bb.x);
                tmp[5] = f2bf((vb.y-mu)*rs*gb.y + bb.y);
                tmp[6] = f2bf((vb.z-mu)*rs*gb.z + bb.z);
                tmp[7] = f2bf((vb.w-mu)*rs*gb.w + bb.w);
                *(uint4*)&As[n*200 + cc] = *(uint4*)tmp;
            }
        }
    }
    __syncthreads();

    // ---- phase B: QKV GEMM, 3 chunks (q,k,v), W frags from L2
    #pragma unroll
    for (int chunk = 0; chunk < 3; chunk++){
        f32x4 acc[3][4];
        #pragma unroll
        for (int nf = 0; nf < 3; nf++)
            #pragma unroll
            for (int mf = 0; mf < 4; mf++)
                acc[nf][mf] = (f32x4){0.f,0.f,0.f,0.f};
        #pragma unroll
        for (int k0 = 0; k0 < C_DIM; k0 += 32){
            bf16x8 a[4], b[3];
            #pragma unroll
            for (int mf = 0; mf < 4; mf++)
                a[mf] = *(const bf16x8*)&As[(mf*16 + lr)*200 + k0 + lg*8];
            #pragma unroll
            for (int nf = 0; nf < 3; nf++)
                b[nf] = *(const bf16x8*)(wt + (size_t)(chunk*192 + wid*48 + nf*16 + lr)*C_DIM + k0 + lg*8);
            #pragma unroll
            for (int nf = 0; nf < 3; nf++)
                #pragma unroll
                for (int mf = 0; mf < 4; mf++)
                    acc[nf][mf] = __builtin_amdgcn_mfma_f32_16x16x32_bf16(a[mf], b[nf], acc[nf][mf], 0, 0, 0);
        }
        unsigned short* dst = (chunk == 0) ? q : (chunk == 1) ? k : v;
        float sc = (chunk == 0) ? QSCALE : 1.f;
        #pragma unroll
        for (int nf = 0; nf < 3; nf++){
            int cc = wid*48 + nf*16 + lr;
            float b = bias[chunk*192 + cc];
            int head = cc >> 5, d = cc & 31;
            unsigned short* dp = dst + ((size_t)(win*HEADS + head) * NTOK) * DH + d;
            #pragma unroll
            for (int mf = 0; mf < 4; mf++)
                #pragma unroll
                for (int r = 0; r < 4; r++){
                    int ntok = mf*16 + lg*4 + r;
                    dp[ntok*DH] = f2bf((acc[nf][mf][r] + b) * sc);
                }
        }
    }
}

// ---------------- K3: MFMA windowed attention. 4 waves/block, 1 (win,head)/wave.
__global__ void k_attn_mfma(const unsigned short* __restrict__ q, const unsigned short* __restrict__ k,
                            const unsigned short* __restrict__ v, const float* __restrict__ bmT,
                            unsigned short* __restrict__ attn_o)
{
    __shared__ __align__(16) unsigned short Vt[4][32*72];
    __shared__ __align__(16) unsigned short Ps[4][64*72];
    const int tid = threadIdx.x, lane = tid & 63, wid = tid >> 6;
    const int wh = blockIdx.x * 4 + wid;
    const int head = wh % HEADS, win = wh / HEADS;
    const int w2 = win % WPI;
    const int type = ((w2 / NSIDE) == 27 ? 2 : 0) + ((w2 % NSIDE) == 27 ? 1 : 0);
    const size_t base = (size_t)wh * (NTOK * DH);
    const int lr = lane & 15, lg = lane >> 4;

    {
        const uint4* vp = (const uint4*)(v + base + lane * DH);
        uint4 va = vp[0], vb = vp[1], vc = vp[2], vd = vp[3];
        unsigned short* dst = &Vt[wid][lane];
        unsigned w0[8] = {va.x, va.y, va.z, va.w, vb.x, vb.y, vb.z, vb.w};
        #pragma unroll
        for (int j = 0; j < 8; j++){
            dst[(2*j)*72]   = (unsigned short)(w0[j] & 0xFFFFu);
            dst[(2*j+1)*72] = (unsigned short)(w0[j] >> 16);
        }
        unsigned w1[8] = {vc.x, vc.y, vc.z, vc.w, vd.x, vd.y, vd.z, vd.w};
        #pragma unroll
        for (int j = 0; j < 8; j++){
            dst[(16+2*j)*72]   = (unsigned short)(w1[j] & 0xFFFFu);
            dst[(16+2*j+1)*72] = (unsigned short)(w1[j] >> 16);
        }
    }

    bf16x8 aq[4], bk[4];
    {
        const unsigned short* qg = q + base + lr * DH + (lg << 3);
        const unsigned short* kg = k + base + lr * DH + (lg << 3);
        #pragma unroll
        for (int i = 0; i < 4; i++){
            aq[i] = *(const bf16x8*)(qg + i * 16 * DH);
            bk[i] = *(const bf16x8*)(kg + i * 16 * DH);
        }
    }

    f32x4 acc[4][4];
    #pragma unroll
    for (int mi = 0; mi < 4; mi++)
        #pragma unroll
        for (int ni = 0; ni < 4; ni++)
            acc[mi][ni] = __builtin_amdgcn_mfma_f32_16x16x32_bf16(aq[mi], bk[ni],
                              (f32x4){0.f,0.f,0.f,0.f}, 0, 0, 0);

    const float* bmBase = bmT + ((size_t)(type * HEADS + head) * 64) * 64;
    #pragma unroll
    for (int mi = 0; mi < 4; mi++)
        #pragma unroll
        for (int ni = 0; ni < 4; ni++){
            float4 bm = *(const float4*)(bmBase + (lr + 16*ni)*64 + lg*4 + 16*mi);
            acc[mi][ni][0] += bm.x; acc[mi][ni][1] += bm.y;
            acc[mi][ni][2] += bm.z; acc[mi][ni][3] += bm.w;
        }

    #pragma unroll
    for (int mi = 0; mi < 4; mi++){
        #pragma unroll
        for (int r = 0; r < 4; r++){
            float mx = fmaxf(fmaxf(acc[mi][0][r], acc[mi][1][r]),
                             fmaxf(acc[mi][2][r], acc[mi][3][r]));
            mx = fmaxf(mx, __shfl_xor(mx, 1));
            mx = fmaxf(mx, __shfl_xor(mx, 2));
            mx = fmaxf(mx, __shfl_xor(mx, 4));
            mx = fmaxf(mx, __shfl_xor(mx, 8));
            float e0 = __expf(acc[mi][0][r] - mx);
            float e1 = __expf(acc[mi][1][r] - mx);
            float e2 = __expf(acc[mi][2][r] - mx);
            float e3 = __expf(acc[mi][3][r] - mx);
            float sum = e0 + e1 + e2 + e3;
            sum += __shfl_xor(sum, 1);
            sum += __shfl_xor(sum, 2);
            sum += __shfl_xor(sum, 4);
            sum += __shfl_xor(sum, 8);
            float inv = 1.f / sum;
            int row = lg*4 + r + 16*mi;
            unsigned short* pr = &Ps[wid][row*72 + lr];
            pr[0]  = f2bf(e0 * inv);
            pr[16] = f2bf(e1 * inv);
            pr[32] = f2bf(e2 * inv);
            pr[48] = f2bf(e3 * inv);
        }
    }

    f32x4 o[4][2];
    #pragma unroll
    for (int mi = 0; mi < 4; mi++)
        #pragma unroll
        for (int ni = 0; ni < 2; ni++)
            o[mi][ni] = (f32x4){0.f,0.f,0.f,0.f};
    #pragma unroll
    for (int kb = 0; kb < 2; kb++){
        bf16x8 ap[4], bv[2];
        #pragma unroll
        for (int mi = 0; mi < 4; mi++)
            ap[mi] = *(const bf16x8*)&Ps[wid][(lr + 16*mi)*72 + (lg<<3) + 32*kb];
        #pragma unroll
        for (int ni = 0; ni < 2; ni++)
            bv[ni] = *(const bf16x8*)&Vt[wid][(lr + 16*ni)*72 + (lg<<3) + 32*kb];
        #pragma unroll
        for (int mi = 0; mi < 4; mi++)
            #pragma unroll
            for (int ni = 0; ni < 2; ni++)
                o[mi][ni] = __builtin_amdgcn_mfma_f32_16x16x32_bf16(ap[mi], bv[ni], o[mi][ni], 0, 0, 0);
    }

    unsigned short* ob = attn_o + ((size_t)win * NTOK) * C_DIM + head * DH;
    #pragma unroll
    for (int mi = 0; mi < 4; mi++)
        #pragma unroll
        for (int ni = 0; ni < 2; ni++)
            #pragma unroll
            for (int r = 0; r < 4; r++){
                int row = lg*4 + r + 16*mi;
                ob[(size_t)row * C_DIM + lr + 16*ni] = f2bf(o[mi][ni][r]);
            }
}

// ---------------- K4: proj GEMM, A staged once, single pass (4 waves x 48 cols)
__global__ void k_proj2(const unsigned short* __restrict__ ain, const unsigned short* __restrict__ wt,
                        const float* __restrict__ bias, const float* __restrict__ x,
                        float* __restrict__ out)
{
    __shared__ __align__(16) unsigned short As[64*200];
    const int tid = threadIdx.x, lane = tid & 63, wid = tid >> 6;
    const int lr = lane & 15, lg = lane >> 4;
    const int t0 = blockIdx.x * 64, win = blockIdx.x;

    {
        int row = tid >> 2, part = tid & 3;
        const unsigned short* gp = ain + (size_t)(t0 + row) * C_DIM;
        #pragma unroll
        for (int j = 0; j < 6; j++){
            int c = part*8 + j*32;
            *(uint4*)&As[row*200 + c] = *(const uint4*)(gp + c);
        }
    }
    __syncthreads();

    f32x4 acc[3][4];
    #pragma unroll
    for (int nf = 0; nf < 3; nf++)
        #pragma unroll
        for (int mf = 0; mf < 4; mf++)
            acc[nf][mf] = (f32x4){0.f,0.f,0.f,0.f};
    #pragma unroll
    for (int k0 = 0; k0 < C_DIM; k0 += 32){
        bf16x8 a[4], b[3];
        #pragma unroll
        for (int mf = 0; mf < 4; mf++)
            a[mf] = *(const bf16x8*)&As[(mf*16 + lr)*200 + k0 + lg*8];
        #pragma unroll
        for (int nf = 0; nf < 3; nf++)
            b[nf] = *(const bf16x8*)(wt + (size_t)(wid*48 + nf*16 + lr)*C_DIM + k0 + lg*8);
        #pragma unroll
        for (int nf = 0; nf < 3; nf++)
            #pragma unroll
            for (int mf = 0; mf < 4; mf++)
                acc[nf][mf] = __builtin_amdgcn_mfma_f32_16x16x32_bf16(a[mf], b[nf], acc[nf][mf], 0, 0, 0);
    }

    const int bimg = win / WPI, w2 = win % WPI;
    const int wi = w2 / NSIDE, wj = w2 % NSIDE;
    #pragma unroll
    for (int mf = 0; mf < 4; mf++){
        #pragma unroll
        for (int r = 0; r < 4; r++){
            int n = mf*16 + lg*4 + r;
            int rr = n >> 3, cc_ = n & 7;
            int hf = wi*8 + rr + 4; if (hf >= IMG) hf -= IMG;
            int wf = wj*8 + cc_ + 4; if (wf >= IMG) wf -= IMG;
            size_t s = ((size_t)bimg*(IMG*IMG) + hf*IMG + wf) * C_DIM;
            #pragma unroll
            for (int nf = 0; nf < 3; nf++){
                int c = wid*48 + nf*16 + lr;
                out[s + c] = x[s + c] + acc[nf][mf][r] + bias[c];
            }
        }
    }
}

// ---------------- K5: fused LN2 + fc1 + GELU + fc2 + residual (proven 265us config)
#define XS_STR 200
#define H1_STR 392
#define O_STR  196
__global__ void k_mlp(float* __restrict__ out,
                      const float* __restrict__ g, const float* __restrict__ bta,
                      const unsigned short* __restrict__ w1, const float* __restrict__ b1,
                      const unsigned short* __restrict__ w2, const float* __restrict__ b2)
{
    __shared__ __align__(16) unsigned short H1u[32*H1_STR];   // 25088 B
    unsigned short* Xs = H1u;
    float* O = (float*)H1u;
    const int tid = threadIdx.x, lane = tid & 63, wid = tid >> 6;
    const int lr = lane & 15, lg = lane >> 4;
    const int t0 = blockIdx.x * 32;

    {
        int row = tid >> 3, part = tid & 7;
        const float* xp = out + (size_t)(t0 + row) * C_DIM + part * 24;
        float vals[24];
        float sum = 0.f, sq = 0.f;
        #pragma unroll
        for (int j = 0; j < 6; j++){
            float4 v4 = *(const float4*)(xp + j*4);
            vals[j*4+0] = v4.x; vals[j*4+1] = v4.y; vals[j*4+2] = v4.z; vals[j*4+3] = v4.w;
            sum += v4.x + v4.y + v4.z + v4.w;
            sq  += v4.x*v4.x + v4.y*v4.y + v4.z*v4.z + v4.w*v4.w;
        }
        sum += __shfl_xor(sum, 1); sq += __shfl_xor(sq, 1);
        sum += __shfl_xor(sum, 2); sq += __shfl_xor(sq, 2);
        sum += __shfl_xor(sum, 4); sq += __shfl_xor(sq, 4);
        float mu = sum * (1.f/192.f);
        float var = sq * (1.f/192.f) - mu*mu;
        float rs = rsqrtf(var + 1e-5f);
        int c0 = part * 24;
        #pragma unroll
        for (int j = 0; j < 3; j++){
            int c = c0 + j*8;
            float4 ga = *(const float4*)(g + c), gb = *(const float4*)(g + c + 4);
            float4 ba = *(const float4*)(bta + c), bb = *(const float4*)(bta + c + 4);
            unsigned short tmp[8];
            tmp[0] = f2bf((vals[j*8+0]-mu)*rs*ga.x + ba.x);
            tmp[1] = f2bf((vals[j*8+1]-mu)*rs*ga.y + ba.y);
            tmp[2] = f2bf((vals[j*8+2]-mu)*rs*ga.z + ba.z);
            tmp[3] = f2bf((vals[j*8+3]-mu)*rs*ga.w + ba.w);
            tmp[4] = f2bf((vals[j*8+4]-mu)*rs*gb.x + bb.x);
            tmp[5] = f2bf((vals[j*8+5]-mu)*rs*gb.y + bb.y);
            tmp[6] = f2bf((vals[j*8+6]-mu)*rs*gb.z + bb.z);
            tmp[7] = f2bf((vals[j*8+7]-mu)*rs*gb.w + bb.w);
            *(uint4*)&Xs[row*XS_STR + c] = *(uint4*)tmp;
        }
    }
    __syncthreads();

    f32x4 acc1[6][2];
    {
        #pragma unroll
        for (int mf = 0; mf < 6; mf++)
            #pragma unroll
            for (int nf = 0; nf < 2; nf++)
                acc1[mf][nf] = (f32x4){0.f,0.f,0.f,0.f};
        #pragma unroll
        for (int k0 = 0; k0 < C_DIM; k0 += 32){
            bf16x8 a[6], b[2];
            #pragma unroll
            for (int mf = 0; mf < 6; mf++)
                a[mf] = *(const bf16x8*)(w1 + (size_t)(wid*96 + mf*16 + lr)*C_DIM + k0 + lg*8);
            #pragma unroll
            for (int nf = 0; nf < 2; nf++)
                b[nf] = *(const bf16x8*)&Xs[(nf*16 + lr)*XS_STR + k0 + lg*8];
            #pragma unroll
            for (int mf = 0; mf < 6; mf++)
                #pragma unroll
                for (int nf = 0; nf < 2; nf++)
                    acc1[mf][nf] = __builtin_amdgcn_mfma_f32_16x16x32_bf16(a[mf], b[nf], acc1[mf][nf], 0, 0, 0);
        }
    }
    __syncthreads();

    {
        #pragma unroll
        for (int mf = 0; mf < 6; mf++){
            int hc = wid*96 + mf*16 + lg*4;
            float4 bb = *(const float4*)(b1 + hc);
            float bias[4] = {bb.x, bb.y, bb.z, bb.w};
            #pragma unroll
            for (int nf = 0; nf < 2; nf++){
                int token = nf*16 + lr;
                float gl[4];
                #pragma unroll
                for (int r = 0; r < 4; r++){
                    float u = acc1[mf][nf][r] + bias[r];
                    gl[r] = 0.5f*u*(1.f + erff(u*0.70710678118654752f));
                }
                uint2 pk; pk.x = pack2(gl[0], gl[1]); pk.y = pack2(gl[2], gl[3]);
                *(uint2*)&H1u[token*H1_STR + hc] = pk;
            }
        }
    }
    __syncthreads();

    f32x4 acc2[2][3];
    {
        #pragma unroll
        for (int rf = 0; rf < 2; rf++)
            #pragma unroll
            for (int cf = 0; cf < 3; cf++)
                acc2[rf][cf] = (f32x4){0.f,0.f,0.f,0.f};
        #pragma unroll
        for (int k0 = 0; k0 < HID; k0 += 32){
            bf16x8 a[2], b[3];
            #pragma unroll
            for (int rf = 0; rf < 2; rf++)
                a[rf] = *(const bf16x8*)&H1u[(rf*16 + lr)*H1_STR + k0 + lg*8];
            #pragma unroll
            for (int cf = 0; cf < 3; cf++)
                b[cf] = *(const bf16x8*)(w2 + (size_t)(wid*48 + cf*16 + lr)*HID + k0 + lg*8);
            #pragma unroll
            for (int rf = 0; rf < 2; rf++)
                #pragma unroll
                for (int cf = 0; cf < 3; cf++)
                    acc2[rf][cf] = __builtin_amdgcn_mfma_f32_16x16x32_bf16(a[rf], b[cf], acc2[rf][cf], 0, 0, 0);
        }
    }
    __syncthreads();

    #pragma unroll
    for (int cf = 0; cf < 3; cf++){
        int c = wid*48 + cf*16 + lr;
        float bias = b2[c];
        #pragma unroll
        for (int rf = 0; rf < 2; rf++)
            #pragma unroll
            for (int r = 0; r < 4; r++)
                O[(rf*16 + lg*4 + r)*O_STR + c] = acc2[rf][cf][r] + bias;
    }
    __syncthreads();

    {
        int row = tid >> 3, part = tid & 7;
        float* op = out + (size_t)(t0 + row) * C_DIM;
        const float* Or = O + row * O_STR;
        #pragma unroll
        for (int j = 0; j < 6; j++){
            int c = part*4 + j*32;
            float4 add = *(const float4*)&Or[c];
            float4 old = *(const float4*)&op[c];
            old.x += add.x; old.y += add.y; old.z += add.z; old.w += add.w;
            *(float4*)&op[c] = old;
        }
    }
}

extern "C" void kernel_launch(void* const* d_in, const int* in_sizes, int n_in,
                              void* d_out, int out_size, void* d_ws, size_t ws_size,
                              hipStream_t stream)
{
    const float* x       = (const float*)d_in[0];
    const float* n1g     = (const float*)d_in[1];
    const float* n1b     = (const float*)d_in[2];
    const float* qkv_w   = (const float*)d_in[3];
    const float* qkv_b   = (const float*)d_in[4];
    const float* proj_w  = (const float*)d_in[5];
    const float* proj_b  = (const float*)d_in[6];
    const float* rtab    = (const float*)d_in[7];
    const float* n2g     = (const float*)d_in[8];
    const float* n2b     = (const float*)d_in[9];
    const float* fc1_w   = (const float*)d_in[10];
    const float* fc1_b   = (const float*)d_in[11];
    const float* fc2_w   = (const float*)d_in[12];
    const float* fc2_b   = (const float*)d_in[13];
    float* out = (float*)d_out;

    char* wsb = (char*)d_ws;
    const size_t SZ = (size_t)T_TOT * C_DIM * 2;   // 77,070,336 bytes
    unsigned short* attn_o = (unsigned short*)(wsb);
    unsigned short* qb   = (unsigned short*)(wsb + SZ);
    unsigned short* kb   = (unsigned short*)(wsb + 2*SZ);
    unsigned short* vb   = (unsigned short*)(wsb + 3*SZ);
    unsigned short* wt_qkv  = (unsigned short*)(wsb + 4*SZ);
    unsigned short* wt_proj = wt_qkv + 576*192;
    unsigned short* wt_fc1  = wt_proj + 192*192;
    unsigned short* wt_fc2  = wt_fc1 + 384*192;
    float*          bmT     = (float*)(wt_fc2 + 384*192);   // 4*6*64*64 f32

    k_prep<<<(393216 + 255)/256, 256, 0, stream>>>(qkv_w, proj_w, fc1_w, fc2_w, rtab,
                                                   wt_qkv, wt_proj, wt_fc1, wt_fc2, bmT);

    k_ln1qkv<<<NWIN, 256, 0, stream>>>(x, n1g, n1b, wt_qkv, qkv_b, qb, kb, vb);
    k_attn_mfma<<<NWIN*HEADS/4, 256, 0, stream>>>(qb, kb, vb, bmT, attn_o);
    k_proj2<<<NWIN, 256, 0, stream>>>(attn_o, wt_proj, proj_b, x, out);
    k_mlp<<<T_TOT/32, 256, 0, stream>>>(out, n2g, n2b, wt_fc1, fc1_b, wt_fc2, fc2_b);
}